// Round 4
// baseline (84.973 us; speedup 1.0000x reference)
//
#include <hip/hip_runtime.h>

#define N_FFT 1024
#define SPLIT0 513
// Swizzle in float2 units: pad 1 float2 every 16 (breaks pow-2 write strides).
#define PAD2(a) ((a) + ((a) >> 4))
#define PPB 2  // row-pairs (complex FFTs) per block

// One block processes PPB pairs of rows. For each pair: z = row0 + i*row1,
// 1024-pt complex FFT (radix-4 Stockham, 5 passes, float2 LDS), untangle the
// two real spectra. All global loads for all PPB pairs issue at kernel entry
// so later pairs' loads are fully hidden behind earlier pairs' compute.
__global__ __launch_bounds__(256) void rfft1024_pairs(const float* __restrict__ x,
                                                      float* __restrict__ out,
                                                      int nrows) {
    __shared__ float2 buf[2][N_FFT + 64];

    const int t = threadIdx.x;
    const int pair0 = blockIdx.x * PPB;

    // Issue ALL global loads up front (float4: thread t gets elems 4t..4t+3).
    float4 ld0[PPB], ld1[PPB];
    #pragma unroll
    for (int q = 0; q < PPB; ++q) {
        const float4* __restrict__ p0 =
            (const float4*)(x + (size_t)(2 * (pair0 + q)) * N_FFT);
        const float4* __restrict__ p1 =
            (const float4*)(x + (size_t)(2 * (pair0 + q) + 1) * N_FFT);
        ld0[q] = p0[t];
        ld1[q] = p1[t];
    }

    float* __restrict__ outr = out;
    float* __restrict__ outi = out + (size_t)nrows * SPLIT0;

    // Initial fill of buf[0] from pair 0.
    {
        const float* a = &ld0[0].x;
        const float* b = &ld1[0].x;
        #pragma unroll
        for (int j = 0; j < 4; ++j) {
            int idx = 4 * t + j;
            buf[0][PAD2(idx)] = make_float2(a[j], b[j]);
        }
    }

    #pragma unroll
    for (int q = 0; q < PPB; ++q) {
        __syncthreads();  // fill(buf0) / untangle(buf1) of prev iter -> pass0

        // 5 radix-4 Stockham DIF passes: pass p reads buf[p&1], writes buf[~p&1].
        // Thread t: m=4^p, k=t&(m-1), jm=t-k. Reads src[t+256r] (contiguous).
        // Twiddle w = exp(-2*pi*i*jm/1024). Writes dst[k + 4*jm + r*m].
        #pragma unroll
        for (int p = 0; p < 5; ++p) {
            const int src = p & 1;
            const int m = 1 << (2 * p);
            const int k = t & (m - 1);
            const int jm = t - k;

            float2 a = buf[src][PAD2(t)];
            float2 b = buf[src][PAD2(t + 256)];
            float2 c = buf[src][PAD2(t + 512)];
            float2 d = buf[src][PAD2(t + 768)];

            float t0r = a.x + c.x, t0i = a.y + c.y;
            float t1r = a.x - c.x, t1i = a.y - c.y;
            float t2r = b.x + d.x, t2i = b.y + d.y;
            float t3r = b.x - d.x, t3i = b.y - d.y;

            float y0r = t0r + t2r, y0i = t0i + t2i;
            float y1r = t1r + t3i, y1i = t1i - t3r;  // t1 + (-i)*t3
            float y2r = t0r - t2r, y2i = t0i - t2i;
            float y3r = t1r - t3i, y3i = t1i + t3r;  // t1 - (-i)*t3

            // Hardware sin/cos: input in REVOLUTIONS. phase = -jm/1024 rev.
            float ph = (float)jm * (-1.0f / 1024.0f);
            float c1 = __builtin_amdgcn_cosf(ph);
            float s1 = __builtin_amdgcn_sinf(ph);
            float c2 = c1 * c1 - s1 * s1, s2 = 2.0f * c1 * s1;
            float c3 = c1 * c2 - s1 * s2, s3 = c1 * s2 + s1 * c2;

            const int dst = src ^ 1;
            const int w0 = k + 4 * jm;
            buf[dst][PAD2(w0)]         = make_float2(y0r, y0i);
            buf[dst][PAD2(w0 + m)]     = make_float2(y1r * c1 - y1i * s1,
                                                     y1r * s1 + y1i * c1);
            buf[dst][PAD2(w0 + 2 * m)] = make_float2(y2r * c2 - y2i * s2,
                                                     y2r * s2 + y2i * c2);
            buf[dst][PAD2(w0 + 3 * m)] = make_float2(y3r * c3 - y3i * s3,
                                                     y3r * s3 + y3i * c3);
            __syncthreads();
        }
        // After pass 4's barrier: buf[0] is dead (pass 4 read it), result in buf[1].

        // Prefill buf[0] for the next pair (loads already long in flight).
        if (q + 1 < PPB) {
            const float* a = &ld0[q + 1].x;
            const float* b = &ld1[q + 1].x;
            #pragma unroll
            for (int j = 0; j < 4; ++j) {
                int idx = 4 * t + j;
                buf[0][PAD2(idx)] = make_float2(a[j], b[j]);
            }
        }

        // Untangle from buf[1]:
        // X0[k] = (Z[k]+conj(Z[N-k]))/2 ; X1[k] = -i/2*(Z[k]-conj(Z[N-k])).
        const size_t row0 = (size_t)(2 * (pair0 + q));
        #pragma unroll
        for (int c = 0; c < 2; ++c) {
            int kk = t + 256 * c;
            float2 z = buf[1][PAD2(kk)];
            int km = (N_FFT - kk) & (N_FFT - 1);
            float2 zm = buf[1][PAD2(km)];
            float X0r = 0.5f * (z.x + zm.x), X0i = 0.5f * (z.y - zm.y);
            float X1r = 0.5f * (z.y + zm.y), X1i = 0.5f * (zm.x - z.x);
            outr[row0 * SPLIT0 + kk]       = X0r;
            outi[row0 * SPLIT0 + kk]       = X0i;
            outr[(row0 + 1) * SPLIT0 + kk] = X1r;
            outi[(row0 + 1) * SPLIT0 + kk] = X1i;
        }
        if (t == 0) {
            // k = 512 (Nyquist): Z[512] = X0[512] + i*X1[512], both real.
            float2 z = buf[1][PAD2(512)];
            outr[row0 * SPLIT0 + 512]       = z.x;
            outi[row0 * SPLIT0 + 512]       = 0.0f;
            outr[(row0 + 1) * SPLIT0 + 512] = z.y;
            outi[(row0 + 1) * SPLIT0 + 512] = 0.0f;
        }
    }
}

extern "C" void kernel_launch(void* const* d_in, const int* in_sizes, int n_in,
                              void* d_out, int out_size, void* d_ws, size_t ws_size,
                              hipStream_t stream) {
    const float* x = (const float*)d_in[0];
    float* out = (float*)d_out;
    const int nrows = in_sizes[0] / N_FFT;  // 8192
    const int npairs = nrows / 2;           // 4096
    rfft1024_pairs<<<npairs / PPB, 256, 0, stream>>>(x, out, nrows);
}